// Round 15
// baseline (255.660 us; speedup 1.0000x reference)
//
#include <hip/hip_runtime.h>
#include <math.h>

typedef unsigned int u32;
typedef unsigned short u16;
typedef __attribute__((ext_vector_type(8))) short bf16x8;
typedef __attribute__((ext_vector_type(4))) float f32x4;

#define NN   40000
#define EE   640000
#define SUBG 400
#define CELLS 100
#define BNEPS 1e-5f
#define GB    2048     // gather blocks
#define GEMMB 625
#define DEGB  1024
#define FILLB 1024

// ---- bf16 helpers ----
__device__ __forceinline__ u32 bf16pair(float a, float b) {
    u32 ua = __float_as_uint(a), ub = __float_as_uint(b);
    ua += 0x7fffu + ((ua >> 16) & 1u);
    ub += 0x7fffu + ((ub >> 16) & 1u);
    return (ua >> 16) | (ub & 0xffff0000u);
}
__device__ __forceinline__ float bflo(u32 u) { return __uint_as_float(u << 16); }
__device__ __forceinline__ float bfhi(u32 u) { return __uint_as_float(u & 0xffff0000u); }

// Compute BN scale/shift into LDS from 8x256 atomic partials (sum | sumsq).
__device__ __forceinline__ void bn_ss_from_part2(const float* __restrict__ part2,
                                                 const float* __restrict__ bng,
                                                 const float* __restrict__ bnb,
                                                 float* ssc, float* ssh, int t) {
    if (t < 128) {
        float s = 0.f, q = 0.f;
#pragma unroll
        for (int g = 0; g < 8; ++g) {
            s += part2[g * 256 + t];
            q += part2[g * 256 + 128 + t];
        }
        float mean = s * (1.0f / NN);
        float var  = q * (1.0f / NN) - mean * mean;
        float sc = bng[t] * rsqrtf(var + BNEPS);
        ssc[t] = sc;
        ssh[t] = bnb[t] - mean * sc;
    }
    __syncthreads();
}

// ---------------- degree count || bf16 weight transposes (merged) ----------------
__global__ __launch_bounds__(256)
void k_degW(const int* __restrict__ dst, int* __restrict__ deg,
            const float* __restrict__ W1, u32* __restrict__ Wt1,
            const float* __restrict__ W2, u32* __restrict__ Wt2,
            const float* __restrict__ wa, u32* __restrict__ Wta) {
    int bid = blockIdx.x;
    int t = threadIdx.x;
    if (bid < DEGB) {
        int i = bid * 256 + t;
        int stride = DEGB * 256;
        for (; i < EE; i += stride) atomicAdd(&deg[dst[i]], 1);
        return;
    }
    int i = (bid - DEGB) * 256 + t;
    if (i < 16384) {
        const float* W = (i < 8192) ? W1 : W2;
        u32* Wt = (i < 8192) ? Wt1 : Wt2;
        int j = i & 8191;
        int n = j >> 6, k2 = (j & 63) * 2;
        Wt[n * 64 + (j & 63)] = bf16pair(W[k2 * 128 + n], W[(k2 + 1) * 128 + n]);
        return;
    }
    i -= 16384;
    if (i < 4096) {
        int n = i >> 6, k2 = (i & 63) * 2;
        Wta[n * 64 + (i & 63)] = bf16pair(wa[k2 * 64 + n], wa[(k2 + 1) * 64 + n]);
    }
}

// ---------------- single-block full exclusive scan + dis (two-pass, no spill) ----------------
__global__ __launch_bounds__(1024)
void k_scan(const int* __restrict__ deg, int* __restrict__ rowstart,
            float* __restrict__ dis) {
    __shared__ int ps[1024];
    int t = threadIdx.x;
    const int4* d4 = (const int4*)deg;
    int sum = 0;
#pragma unroll
    for (int j = 0; j < 10; ++j) {
        int i4 = t * 10 + j;
        if (i4 < 10000) {
            int4 v = d4[i4];
            sum += v.x + v.y + v.z + v.w;
        }
    }
    ps[t] = sum;
    __syncthreads();
    for (int off = 1; off < 1024; off <<= 1) {
        int add = (t >= off) ? ps[t - off] : 0;
        __syncthreads();
        ps[t] += add;
        __syncthreads();
    }
    int run = ps[t] - sum;
#pragma unroll
    for (int j = 0; j < 10; ++j) {
        int i4 = t * 10 + j;
        if (i4 < 10000) {
            int4 v = d4[i4];
            int4 r;
            r.x = run;
            r.y = run + v.x;
            r.z = r.y + v.y;
            r.w = r.z + v.z;
            run = r.w + v.w;
            *(int4*)&rowstart[i4 * 4] = r;
            float4 dv;
            dv.x = rsqrtf((float)(v.x + 1));
            dv.y = rsqrtf((float)(v.y + 1));
            dv.z = rsqrtf((float)(v.z + 1));
            dv.w = rsqrtf((float)(v.w + 1));
            *(float4*)&dis[i4 * 4] = dv;
        }
    }
    if (t == 0) rowstart[NN] = EE;
}

// ---------------- fill CSR (u16) || conv1 MFMA GEMM (merged, non-partitioned) ----------------
__global__ __launch_bounds__(256)
void k_fillgemm(const int* __restrict__ src, const int* __restrict__ dst,
                const int* __restrict__ rowstart, int* __restrict__ cursor,
                u16* __restrict__ csr16,
                const float* __restrict__ X, const u32* __restrict__ Wt,
                u32* __restrict__ Yb, const float* __restrict__ dis) {
    int bid = blockIdx.x;
    int t = threadIdx.x;
    if (bid < FILLB) {
        int i = bid * 256 + t;
        int stride = FILLB * 256;
        for (; i < EE; i += stride) {
            int d = dst[i];
            int slot = rowstart[d] + atomicAdd(&cursor[d], 1);
            csr16[slot] = (u16)src[i];
        }
        return;
    }
    int l = t & 63, wv = t >> 6;
    int rowbase = (bid - FILLB) * 64 + wv * 16;
    int ml = l & 15, kg = l >> 4;

    f32x4 acc[8];
#pragma unroll
    for (int nt = 0; nt < 8; ++nt) acc[nt] = (f32x4){0.f, 0.f, 0.f, 0.f};
    const float* xr = X + (long)(rowbase + ml) * 128;
#pragma unroll
    for (int kk = 0; kk < 4; ++kk) {
        int k0 = kk * 32 + kg * 8;
        float4 xa = *(const float4*)&xr[k0];
        float4 xb = *(const float4*)&xr[k0 + 4];
        union { u32 u[4]; bf16x8 v; } af;
        af.u[0] = bf16pair(xa.x, xa.y);
        af.u[1] = bf16pair(xa.z, xa.w);
        af.u[2] = bf16pair(xb.x, xb.y);
        af.u[3] = bf16pair(xb.z, xb.w);
#pragma unroll
        for (int nt = 0; nt < 8; ++nt) {
            bf16x8 b = *(const bf16x8*)&Wt[(nt * 16 + ml) * 64 + (k0 >> 1)];
            acc[nt] = __builtin_amdgcn_mfma_f32_16x16x32_bf16(af.v, b, acc[nt], 0, 0, 0);
        }
    }
#pragma unroll
    for (int r = 0; r < 4; ++r) {
        int m = rowbase + kg * 4 + r;
        float dd = dis[m];
        long obase = (long)m * 64;
#pragma unroll
        for (int nt = 0; nt < 8; ++nt) {
            float v = acc[nt][r] * dd;
            float v2 = __shfl_xor(v, 1);
            if ((l & 1) == 0)
                Yb[obase + nt * 8 + (ml >> 1)] = bf16pair(v, v2);
        }
    }
}

// ---------------- gather + BN partials -> 8x256 atomic buffer ----------------
__global__ __launch_bounds__(256)
void k_gather_stats(const uint4* __restrict__ Hb, const int* __restrict__ rowstart,
                    const u16* __restrict__ csr16, const float* __restrict__ dis,
                    const float* __restrict__ bias, u32* __restrict__ F1b,
                    float* __restrict__ part2) {
    __shared__ float ls[1024], lq[1024];
    int t = threadIdx.x;
    int lane = t & 63, wv = t >> 6;
    int gw = blockIdx.x * 4 + wv;
    int g = lane >> 4, p = lane & 15;
    int c0 = p * 8 + g * 2;
    float2 bb = *(const float2*)&bias[c0];
    float s0 = 0.f, s1 = 0.f, q0 = 0.f, q1 = 0.f;

    for (int node = gw; node < NN; node += GB * 4) {
        float a0 = 0.f, a1 = 0.f, a2 = 0.f, a3 = 0.f, a4 = 0.f, a5 = 0.f, a6 = 0.f, a7 = 0.f;
        if (g == 0) {
            uint4 h = Hb[node * 16 + p];
            a0 = bflo(h.x); a1 = bfhi(h.x);
            a2 = bflo(h.y); a3 = bfhi(h.y);
            a4 = bflo(h.z); a5 = bfhi(h.z);
            a6 = bflo(h.w); a7 = bfhi(h.w);
        }
        int e1 = rowstart[node + 1];
        int e = rowstart[node] + g;
        for (; e + 4 < e1; e += 8) {
            int sA = csr16[e];
            int sB = csr16[e + 4];
            uint4 h0 = Hb[sA * 16 + p];
            uint4 h1 = Hb[sB * 16 + p];
            a0 += bflo(h0.x); a1 += bfhi(h0.x);
            a2 += bflo(h0.y); a3 += bfhi(h0.y);
            a4 += bflo(h0.z); a5 += bfhi(h0.z);
            a6 += bflo(h0.w); a7 += bfhi(h0.w);
            a0 += bflo(h1.x); a1 += bfhi(h1.x);
            a2 += bflo(h1.y); a3 += bfhi(h1.y);
            a4 += bflo(h1.z); a5 += bfhi(h1.z);
            a6 += bflo(h1.w); a7 += bfhi(h1.w);
        }
        if (e < e1) {
            int sA = csr16[e];
            uint4 h0 = Hb[sA * 16 + p];
            a0 += bflo(h0.x); a1 += bfhi(h0.x);
            a2 += bflo(h0.y); a3 += bfhi(h0.y);
            a4 += bflo(h0.z); a5 += bfhi(h0.z);
            a6 += bflo(h0.w); a7 += bfhi(h0.w);
        }
#pragma unroll
        for (int m = 16; m <= 32; m <<= 1) {
            a0 += __shfl_xor(a0, m); a1 += __shfl_xor(a1, m);
            a2 += __shfl_xor(a2, m); a3 += __shfl_xor(a3, m);
            a4 += __shfl_xor(a4, m); a5 += __shfl_xor(a5, m);
            a6 += __shfl_xor(a6, m); a7 += __shfl_xor(a7, m);
        }
        float dd = dis[node];
        float x = (g == 0) ? a0 : (g == 1) ? a2 : (g == 2) ? a4 : a6;
        float y = (g == 0) ? a1 : (g == 1) ? a3 : (g == 2) ? a5 : a7;
        x = fmaf(x, dd, bb.x);
        y = fmaf(y, dd, bb.y);
        u32 pw = bf16pair(x, y);
        F1b[node * 64 + (c0 >> 1)] = pw;
        float rx = bflo(pw), ry = bfhi(pw);
        s0 += rx; s1 += ry; q0 += rx * rx; q1 += ry * ry;
    }
    ls[wv * 128 + c0] = s0; ls[wv * 128 + c0 + 1] = s1;
    lq[wv * 128 + c0] = q0; lq[wv * 128 + c0 + 1] = q1;
    __syncthreads();
    if (t < 128) {
        float S = ls[t] + ls[128 + t] + ls[256 + t] + ls[384 + t];
        float Q = lq[t] + lq[128 + t] + lq[256 + t] + lq[384 + t];
        float* row = part2 + (blockIdx.x & 7) * 256;
        atomicAdd(&row[t], S);
        atomicAdd(&row[128 + t], Q);
    }
}

// ---------------- conv2 MFMA GEMM: bf16 in, in-kernel BN1 scale/shift, dis-prescaled out ----------------
__global__ __launch_bounds__(256)
void k_gemm_bf16(const u32* __restrict__ Xb, const u32* __restrict__ Wt,
                 u32* __restrict__ Yb, const float* __restrict__ part2,
                 const float* __restrict__ bng, const float* __restrict__ bnb,
                 const float* __restrict__ dis) {
    __shared__ float ssc[128], ssh[128];
    int t = threadIdx.x;
    bn_ss_from_part2(part2, bng, bnb, ssc, ssh, t);

    int l = t & 63, wv = t >> 6;
    int rowbase = blockIdx.x * 64 + wv * 16;
    int ml = l & 15, kg = l >> 4;

    f32x4 acc[8];
#pragma unroll
    for (int nt = 0; nt < 8; ++nt) acc[nt] = (f32x4){0.f, 0.f, 0.f, 0.f};
    const u32* xr = Xb + (long)(rowbase + ml) * 64;
#pragma unroll
    for (int kk = 0; kk < 4; ++kk) {
        int k0 = kk * 32 + kg * 8;
        uint4 xw = *(const uint4*)&xr[k0 >> 1];
        float f0 = bflo(xw.x), f1 = bfhi(xw.x), f2 = bflo(xw.y), f3 = bfhi(xw.y);
        float f4 = bflo(xw.z), f5 = bfhi(xw.z), f6 = bflo(xw.w), f7 = bfhi(xw.w);
        float4 sca = *(const float4*)&ssc[k0];
        float4 sha = *(const float4*)&ssh[k0];
        float4 scb = *(const float4*)&ssc[k0 + 4];
        float4 shb = *(const float4*)&ssh[k0 + 4];
        f0 = fmaxf(fmaf(f0, sca.x, sha.x), 0.f);
        f1 = fmaxf(fmaf(f1, sca.y, sha.y), 0.f);
        f2 = fmaxf(fmaf(f2, sca.z, sha.z), 0.f);
        f3 = fmaxf(fmaf(f3, sca.w, sha.w), 0.f);
        f4 = fmaxf(fmaf(f4, scb.x, shb.x), 0.f);
        f5 = fmaxf(fmaf(f5, scb.y, shb.y), 0.f);
        f6 = fmaxf(fmaf(f6, scb.z, shb.z), 0.f);
        f7 = fmaxf(fmaf(f7, scb.w, shb.w), 0.f);
        union { u32 u[4]; bf16x8 v; } af;
        af.u[0] = bf16pair(f0, f1);
        af.u[1] = bf16pair(f2, f3);
        af.u[2] = bf16pair(f4, f5);
        af.u[3] = bf16pair(f6, f7);
#pragma unroll
        for (int nt = 0; nt < 8; ++nt) {
            bf16x8 b = *(const bf16x8*)&Wt[(nt * 16 + ml) * 64 + (k0 >> 1)];
            acc[nt] = __builtin_amdgcn_mfma_f32_16x16x32_bf16(af.v, b, acc[nt], 0, 0, 0);
        }
    }
#pragma unroll
    for (int r = 0; r < 4; ++r) {
        int m = rowbase + kg * 4 + r;
        float dd = dis[m];
        long obase = (long)m * 64;
#pragma unroll
        for (int nt = 0; nt < 8; ++nt) {
            float v = acc[nt][r] * dd;
            float v2 = __shfl_xor(v, 1);
            if ((l & 1) == 0)
                Yb[obase + nt * 8 + (ml >> 1)] = bf16pair(v, v2);
        }
    }
}

// ---------------- k_scoremb: in-kernel BN2 + emb write + MFMA attention scores ----------------
__global__ __launch_bounds__(256)
void k_scoremb(const u32* __restrict__ F1b, const float* __restrict__ part2,
               const float* __restrict__ bng, const float* __restrict__ bnb,
               float* __restrict__ emb,
               const u32* __restrict__ Wta, const float* __restrict__ b1,
               const float* __restrict__ w2, const float* __restrict__ b2,
               float* __restrict__ scores) {
    __shared__ float ssc[128], ssh[128];
    int t = threadIdx.x;
    bn_ss_from_part2(part2, bng, bnb, ssc, ssh, t);

    int l = t & 63, wv = t >> 6;
    int rowbase = blockIdx.x * 64 + wv * 16;
    int ml = l & 15, kg = l >> 4;

    f32x4 acc[4];
#pragma unroll
    for (int nt = 0; nt < 4; ++nt) acc[nt] = (f32x4){0.f, 0.f, 0.f, 0.f};
    const u32* xr = F1b + (long)(rowbase + ml) * 64;
    float* er = emb + (long)(rowbase + ml) * 128;
#pragma unroll
    for (int kk = 0; kk < 4; ++kk) {
        int k0 = kk * 32 + kg * 8;
        uint4 xw = *(const uint4*)&xr[k0 >> 1];
        float f0 = bflo(xw.x), f1 = bfhi(xw.x), f2 = bflo(xw.y), f3 = bfhi(xw.y);
        float f4 = bflo(xw.z), f5 = bfhi(xw.z), f6 = bflo(xw.w), f7 = bfhi(xw.w);
        float4 sca = *(const float4*)&ssc[k0];
        float4 sha = *(const float4*)&ssh[k0];
        float4 scb = *(const float4*)&ssc[k0 + 4];
        float4 shb = *(const float4*)&ssh[k0 + 4];
        f0 = fmaxf(fmaf(f0, sca.x, sha.x), 0.f);
        f1 = fmaxf(fmaf(f1, sca.y, sha.y), 0.f);
        f2 = fmaxf(fmaf(f2, sca.z, sha.z), 0.f);
        f3 = fmaxf(fmaf(f3, sca.w, sha.w), 0.f);
        f4 = fmaxf(fmaf(f4, scb.x, shb.x), 0.f);
        f5 = fmaxf(fmaf(f5, scb.y, shb.y), 0.f);
        f6 = fmaxf(fmaf(f6, scb.z, shb.z), 0.f);
        f7 = fmaxf(fmaf(f7, scb.w, shb.w), 0.f);
        float4 e0 = { f0, f1, f2, f3 };
        float4 e1 = { f4, f5, f6, f7 };
        *(float4*)&er[k0] = e0;
        *(float4*)&er[k0 + 4] = e1;
        union { u32 u[4]; bf16x8 v; } af;
        af.u[0] = bf16pair(f0, f1);
        af.u[1] = bf16pair(f2, f3);
        af.u[2] = bf16pair(f4, f5);
        af.u[3] = bf16pair(f6, f7);
#pragma unroll
        for (int nt = 0; nt < 4; ++nt) {
            bf16x8 b = *(const bf16x8*)&Wta[(nt * 16 + ml) * 64 + (k0 >> 1)];
            acc[nt] = __builtin_amdgcn_mfma_f32_16x16x32_bf16(af.v, b, acc[nt], 0, 0, 0);
        }
    }
    float b1v[4], w2v[4];
#pragma unroll
    for (int nt = 0; nt < 4; ++nt) {
        b1v[nt] = b1[nt * 16 + ml];
        w2v[nt] = w2[nt * 16 + ml];
    }
    float b2v = b2[0];
#pragma unroll
    for (int r = 0; r < 4; ++r) {
        float s = tanhf(acc[0][r] + b1v[0]) * w2v[0]
                + tanhf(acc[1][r] + b1v[1]) * w2v[1]
                + tanhf(acc[2][r] + b1v[2]) * w2v[2]
                + tanhf(acc[3][r] + b1v[3]) * w2v[3];
        s += __shfl_xor(s, 1);
        s += __shfl_xor(s, 2);
        s += __shfl_xor(s, 4);
        s += __shfl_xor(s, 8);
        if (ml == 0) scores[rowbase + kg * 4 + r] = s + b2v;
    }
}

// ---------------- k_pool4: in-kernel BN2 + softmax + partial pool ----------------
__global__ __launch_bounds__(256)
void k_pool4(const u32* __restrict__ F1b, const float* __restrict__ part2,
             const float* __restrict__ bng, const float* __restrict__ bnb,
             const float* __restrict__ scores, float* __restrict__ pp) {
    __shared__ float ssc[128], ssh[128];
    __shared__ float sl[SUBG];
    __shared__ float red[256];
    __shared__ float rbuf[512];
    int b = blockIdx.x;
    int c = b >> 2, q = b & 3;
    int t = threadIdx.x;
    int base = c * SUBG;
    bn_ss_from_part2(part2, bng, bnb, ssc, ssh, t);

    float lmax = -1e30f;
    for (int i = t; i < SUBG; i += 256) {
        float v = scores[base + i];
        sl[i] = v;
        lmax = fmaxf(lmax, v);
    }
    red[t] = lmax;
    __syncthreads();
    for (int off = 128; off > 0; off >>= 1) {
        if (t < off) red[t] = fmaxf(red[t], red[t + off]);
        __syncthreads();
    }
    float mx = red[0];
    __syncthreads();
    float lsum = 0.f;
    for (int i = t; i < SUBG; i += 256) {
        float e = __expf(sl[i] - mx);
        sl[i] = e;
        lsum += e;
    }
    red[t] = lsum;
    __syncthreads();
    for (int off = 128; off > 0; off >>= 1) {
        if (t < off) red[t] += red[t + off];
        __syncthreads();
    }
    float inv = 1.0f / red[0];
    __syncthreads();

    int cc = t & 63, gp = t >> 6;
    float2 scv = *(const float2*)&ssc[2 * cc];
    float2 shv = *(const float2*)&ssh[2 * cc];
    int g0 = q * 100 + gp * 25;
    float a0 = 0.f, a1 = 0.f;
#pragma unroll 5
    for (int j = 0; j < 25; ++j) {
        int gg = g0 + j;
        u32 v = F1b[(long)(base + gg) * 64 + cc];
        float w = sl[gg] * inv;
        float x0 = fmaxf(fmaf(bflo(v), scv.x, shv.x), 0.f);
        float x1 = fmaxf(fmaf(bfhi(v), scv.y, shv.y), 0.f);
        a0 += w * x0;
        a1 += w * x1;
    }
    rbuf[gp * 128 + 2 * cc] = a0;
    rbuf[gp * 128 + 2 * cc + 1] = a1;
    __syncthreads();
    if (t < 128)
        pp[b * 128 + t] = rbuf[t] + rbuf[128 + t] + rbuf[256 + t] + rbuf[384 + t];
}

// ---------------- k_head1r: sum quarters + fc head1 + atomic BN stats ----------------
__global__ __launch_bounds__(128)
void k_head1r(const float* __restrict__ pp, const float* __restrict__ fc_w,
              const float* __restrict__ fc_b, float* __restrict__ y1pre,
              float* __restrict__ hstats) {
    __shared__ float pr[128];
    int c = blockIdx.x, t = threadIdx.x;
    pr[t] = pp[(c * 4 + 0) * 128 + t] + pp[(c * 4 + 1) * 128 + t]
          + pp[(c * 4 + 2) * 128 + t] + pp[(c * 4 + 3) * 128 + t];
    __syncthreads();
    float a1 = fc_b[t];
#pragma unroll 4
    for (int k = 0; k < 128; ++k) a1 = fmaf(pr[k], fc_w[k * 128 + t], a1);
    y1pre[c * 128 + t] = a1;
    atomicAdd(&hstats[t], a1);
    atomicAdd(&hstats[128 + t], a1 * a1);
}

// ---------------- k_tail: BN-e apply + bottleneck + BN-b + output (1 block) ----------------
__global__ __launch_bounds__(256)
void k_tail(const float* __restrict__ y1pre, const float* __restrict__ hstats,
            const float* __restrict__ bne_g, const float* __restrict__ bne_b,
            const float* __restrict__ bot_w, const float* __restrict__ bot_b,
            const float* __restrict__ bnb_g, const float* __restrict__ bnb_b,
            float* __restrict__ y_out) {
    __shared__ float Y1[CELLS * 128];   // 51.2 KB
    __shared__ float Y2[CELLS * 32];    // 12.8 KB
    __shared__ float sc1[128], sh1[128];
    __shared__ float red[256], red2[256];
    int t = threadIdx.x;
    if (t < 128) {
        float s = hstats[t], q = hstats[128 + t];
        float mean = s * 0.01f, var = q * 0.01f - mean * mean;
        float sc = bne_g[t] * rsqrtf(var + BNEPS);
        sc1[t] = sc; sh1[t] = bne_b[t] - mean * sc;
    }
    __syncthreads();
    for (int i = t; i < CELLS * 128; i += 256) {
        int col = i & 127;
        Y1[i] = fmaxf(fmaf(y1pre[i], sc1[col], sh1[col]), 0.f);
    }
    __syncthreads();

    int col2 = t & 31, g2 = t >> 5;     // 8 cell-groups
    float s2 = 0.f, q2 = 0.f;
    for (int j = 0; j < 13; ++j) {
        int c = g2 + 8 * j;
        if (c < CELLS) {
            float a = bot_b[col2];
#pragma unroll 4
            for (int k = 0; k < 128; ++k) a = fmaf(Y1[c * 128 + k], bot_w[k * 32 + col2], a);
            Y2[c * 32 + col2] = a;
            s2 += a; q2 += a * a;
        }
    }
    red[t] = s2; red2[t] = q2;
    __syncthreads();
    if (t < 32) {
        float S = 0.f, Q = 0.f;
#pragma unroll
        for (int u = 0; u < 8; ++u) { S += red[u * 32 + t]; Q += red2[u * 32 + t]; }
        float mean = S * 0.01f, var = Q * 0.01f - mean * mean;
        float v = bnb_g[t] * rsqrtf(var + BNEPS);
        red[t] = v; red2[t] = bnb_b[t] - mean * v;
    }
    __syncthreads();
    for (int i = t; i < CELLS * 32; i += 256)
        y_out[i] = fmaxf(fmaf(Y2[i], red[i & 31], red2[i & 31]), 0.f);
}

// ---------------- launcher ----------------
extern "C" void kernel_launch(void* const* d_in, const int* in_sizes, int n_in,
                              void* d_out, int out_size, void* d_ws, size_t ws_size,
                              hipStream_t stream) {
    const float* x        = (const float*)d_in[0];
    const int*   ei       = (const int*)d_in[1];
    const float* conv1_w  = (const float*)d_in[2];
    const float* conv1_b  = (const float*)d_in[3];
    const float* bn1_g    = (const float*)d_in[4];
    const float* bn1_b    = (const float*)d_in[5];
    const float* conv2_w  = (const float*)d_in[6];
    const float* conv2_b  = (const float*)d_in[7];
    const float* bn2_g    = (const float*)d_in[8];
    const float* bn2_b    = (const float*)d_in[9];
    const float* att_w1   = (const float*)d_in[10];
    const float* att_b1   = (const float*)d_in[11];
    const float* att_w2   = (const float*)d_in[12];
    const float* att_b2   = (const float*)d_in[13];
    const float* fc_w     = (const float*)d_in[14];
    const float* fc_b     = (const float*)d_in[15];
    const float* bne_g    = (const float*)d_in[16];
    const float* bne_b    = (const float*)d_in[17];
    const float* bot_w    = (const float*)d_in[18];
    const float* bot_b    = (const float*)d_in[19];
    const float* bnb_g    = (const float*)d_in[20];
    const float* bnb_b    = (const float*)d_in[21];

    const int* src = ei;
    const int* dst = ei + EE;

    float* y_out   = (float*)d_out;            // [100,32]
    float* emb_out = y_out + CELLS * 32;       // [40000,128]

    float* ws = (float*)d_ws;
    u32*   Hb     = (u32*)ws;                  // N*64
    u32*   F1b    = Hb + (long)NN * 64;        // N*64
    float* dis    = (float*)(F1b + (long)NN * 64);  // N
    float* y1pre  = dis + NN;                  // C*128
    float* scores = y1pre + CELLS * 128;       // N
    float* pp     = scores + NN;               // 400*128
    u32*   Wt1    = (u32*)(pp + 400 * 128);    // 8192
    u32*   Wt2    = Wt1 + 8192;                // 8192
    u32*   Wta    = Wt2 + 8192;                // 4096
    // zeroed region (one memset): deg, cursor, part2A, part2B, hstats
    int*   deg    = (int*)(Wta + 4096);        // N
    int*   cursor = deg + NN;                  // N
    float* part2A = (float*)(cursor + NN);     // 8*256
    float* part2B = part2A + 2048;             // 8*256
    float* hstats = part2B + 2048;             // 256
    int*   rowstart = (int*)(hstats + 256);    // N+1
    u16*   csr16  = (u16*)(rowstart + NN + 1); // E u16

    // 1. zero deg + cursor + part2A/B + hstats (contiguous)
    hipMemsetAsync(deg, 0, (size_t)(2 * NN + 2048 + 2048 + 256) * sizeof(int), stream);
    // 2. degree count || weight transposes
    k_degW<<<DEGB + 80, 256, 0, stream>>>(dst, deg, conv1_w, Wt1, conv2_w, Wt2,
                                          att_w1, Wta);
    // 3. scan -> rowstart, dis
    k_scan<<<1, 1024, 0, stream>>>(deg, rowstart, dis);
    // 4. fill CSR (u16) || conv1 GEMM (dis-prescaled out)
    k_fillgemm<<<FILLB + GEMMB, 256, 0, stream>>>(src, dst, rowstart, cursor, csr16,
                                                  x, Wt1, Hb, dis);
    // 5. conv1 gather + stats -> part2A
    k_gather_stats<<<GB, 256, 0, stream>>>((const uint4*)Hb, rowstart, csr16, dis,
                                           conv1_b, F1b, part2A);
    // 6. conv2 GEMM (in-kernel BN1 from part2A)
    k_gemm_bf16<<<GEMMB, 256, 0, stream>>>(F1b, Wt2, Hb, part2A, bn1_g, bn1_b, dis);
    // 7. conv2 gather + stats -> part2B
    k_gather_stats<<<GB, 256, 0, stream>>>((const uint4*)Hb, rowstart, csr16, dis,
                                           conv2_b, F1b, part2B);
    // 8. BN2+ReLU + emb + MFMA scores (in-kernel BN2 from part2B)
    k_scoremb<<<GEMMB, 256, 0, stream>>>(F1b, part2B, bn2_g, bn2_b, emb_out,
                                         Wta, att_b1, att_w2, att_b2, scores);
    // 9. softmax + partial pool (in-kernel BN2)
    k_pool4<<<4 * CELLS, 256, 0, stream>>>(F1b, part2B, bn2_g, bn2_b, scores, pp);
    // 10. sum partials + fc head1 + stats
    k_head1r<<<CELLS, 128, 0, stream>>>(pp, fc_w, fc_b, y1pre, hstats);
    // 11. tail: BN-e + bottleneck + BN-b + output
    k_tail<<<1, 256, 0, stream>>>(y1pre, hstats, bne_g, bne_b, bot_w, bot_b,
                                  bnb_g, bnb_b, y_out);
}

// Round 16
// 235.150 us; speedup vs baseline: 1.0872x; 1.0872x over previous
//
#include <hip/hip_runtime.h>
#include <math.h>

typedef unsigned int u32;
typedef __attribute__((ext_vector_type(8))) short bf16x8;
typedef __attribute__((ext_vector_type(4))) float f32x4;

#define NN   40000
#define EE   640000
#define SUBG 400
#define CELLS 100
#define BNEPS 1e-5f
#define GB    2048     // gather blocks
#define GEMMB 625
#define DEGB  512
#define FILLB 1024
#define SCALEB 2500    // NN*16 uint4 / 256

// ---- bf16 helpers ----
__device__ __forceinline__ u32 bf16pair(float a, float b) {
    u32 ua = __float_as_uint(a), ub = __float_as_uint(b);
    ua += 0x7fffu + ((ua >> 16) & 1u);
    ub += 0x7fffu + ((ub >> 16) & 1u);
    return (ua >> 16) | (ub & 0xffff0000u);
}
__device__ __forceinline__ float bflo(u32 u) { return __uint_as_float(u << 16); }
__device__ __forceinline__ float bfhi(u32 u) { return __uint_as_float(u & 0xffff0000u); }

// ---------------- init: zero deg/cursor + bf16-transpose weights + zero head stats ----------------
__global__ void k_init(int* deg_cursor, const float* W1, u32* Wt1,
                       const float* W2, u32* Wt2, const float* wa, u32* Wta,
                       float* hstats) {
    int i = blockIdx.x * 256 + threadIdx.x;
    if (i < 2 * NN) { deg_cursor[i] = 0; return; }
    i -= 2 * NN;
    if (i < 16384) {
        const float* W = (i < 8192) ? W1 : W2;
        u32* Wt = (i < 8192) ? Wt1 : Wt2;
        int j = i & 8191;
        int n = j >> 6, k2 = (j & 63) * 2;
        Wt[n * 64 + (j & 63)] = bf16pair(W[k2 * 128 + n], W[(k2 + 1) * 128 + n]);
        return;
    }
    i -= 16384;
    if (i < 4096) {
        int n = i >> 6, k2 = (i & 63) * 2;
        Wta[n * 64 + (i & 63)] = bf16pair(wa[k2 * 64 + n], wa[(k2 + 1) * 64 + n]);
        return;
    }
    i -= 4096;
    if (i < 320) hstats[i] = 0.f;
}

// ---------------- conv1 MFMA GEMM (unscaled) || degree count (merged dispatch) ----------------
__global__ __launch_bounds__(256)
void k_gemmdeg(const float* __restrict__ X, const u32* __restrict__ Wt,
               u32* __restrict__ Yb, const int* __restrict__ dst,
               int* __restrict__ deg) {
    int bid = blockIdx.x;
    int t = threadIdx.x;
    if (bid >= GEMMB) {
        int i = (bid - GEMMB) * 256 + t;
        int stride = DEGB * 256;
        for (; i < EE; i += stride) atomicAdd(&deg[dst[i]], 1);
        return;
    }
    int l = t & 63, wv = t >> 6;
    int rowbase = bid * 64 + wv * 16;
    int ml = l & 15, kg = l >> 4;

    f32x4 acc[8];
#pragma unroll
    for (int nt = 0; nt < 8; ++nt) acc[nt] = (f32x4){0.f, 0.f, 0.f, 0.f};
    const float* xr = X + (long)(rowbase + ml) * 128;
#pragma unroll
    for (int kk = 0; kk < 4; ++kk) {
        int k0 = kk * 32 + kg * 8;
        float4 xa = *(const float4*)&xr[k0];
        float4 xb = *(const float4*)&xr[k0 + 4];
        union { u32 u[4]; bf16x8 v; } af;
        af.u[0] = bf16pair(xa.x, xa.y);
        af.u[1] = bf16pair(xa.z, xa.w);
        af.u[2] = bf16pair(xb.x, xb.y);
        af.u[3] = bf16pair(xb.z, xb.w);
#pragma unroll
        for (int nt = 0; nt < 8; ++nt) {
            bf16x8 b = *(const bf16x8*)&Wt[(nt * 16 + ml) * 64 + (k0 >> 1)];
            acc[nt] = __builtin_amdgcn_mfma_f32_16x16x32_bf16(af.v, b, acc[nt], 0, 0, 0);
        }
    }
#pragma unroll
    for (int r = 0; r < 4; ++r) {
        int m = rowbase + kg * 4 + r;
        long obase = (long)m * 64;
#pragma unroll
        for (int nt = 0; nt < 8; ++nt) {
            float v = acc[nt][r];
            float v2 = __shfl_xor(v, 1);
            if ((l & 1) == 0)
                Yb[obase + nt * 8 + (ml >> 1)] = bf16pair(v, v2);
        }
    }
}

// ---------------- single-block full exclusive scan + dis (two-pass, no spill) ----------------
__global__ __launch_bounds__(1024)
void k_scan(const int* __restrict__ deg, int* __restrict__ rowstart,
            float* __restrict__ dis) {
    __shared__ int ps[1024];
    int t = threadIdx.x;
    const int4* d4 = (const int4*)deg;
    int sum = 0;
#pragma unroll
    for (int j = 0; j < 10; ++j) {
        int i4 = t * 10 + j;
        if (i4 < 10000) {
            int4 v = d4[i4];
            sum += v.x + v.y + v.z + v.w;
        }
    }
    ps[t] = sum;
    __syncthreads();
    for (int off = 1; off < 1024; off <<= 1) {
        int add = (t >= off) ? ps[t - off] : 0;
        __syncthreads();
        ps[t] += add;
        __syncthreads();
    }
    int run = ps[t] - sum;
#pragma unroll
    for (int j = 0; j < 10; ++j) {
        int i4 = t * 10 + j;
        if (i4 < 10000) {
            int4 v = d4[i4];
            int4 r;
            r.x = run;
            r.y = run + v.x;
            r.z = r.y + v.y;
            r.w = r.z + v.z;
            run = r.w + v.w;
            *(int4*)&rowstart[i4 * 4] = r;
            float4 dv;
            dv.x = rsqrtf((float)(v.x + 1));
            dv.y = rsqrtf((float)(v.y + 1));
            dv.z = rsqrtf((float)(v.z + 1));
            dv.w = rsqrtf((float)(v.w + 1));
            *(float4*)&dis[i4 * 4] = dv;
        }
    }
    if (t == 0) rowstart[NN] = EE;
}

// ---------------- fill CSR || scale Hb by dis (merged dispatch) ----------------
__global__ __launch_bounds__(256)
void k_fillscale(const int* __restrict__ src, const int* __restrict__ dst,
                 const int* __restrict__ rowstart, int* __restrict__ cursor,
                 int* __restrict__ csr_src, uint4* __restrict__ Hb,
                 const float* __restrict__ dis) {
    int bid = blockIdx.x;
    int t = threadIdx.x;
    if (bid < FILLB) {
        int i = bid * 256 + t;
        int stride = FILLB * 256;
        for (; i < EE; i += stride) {
            int d = dst[i];
            int slot = rowstart[d] + atomicAdd(&cursor[d], 1);
            csr_src[slot] = src[i];
        }
        return;
    }
    int i = (bid - FILLB) * 256 + t;   // uint4 index, NN*16 total
    float dd = dis[i >> 4];
    uint4 v = Hb[i];
    v.x = bf16pair(bflo(v.x) * dd, bfhi(v.x) * dd);
    v.y = bf16pair(bflo(v.y) * dd, bfhi(v.y) * dd);
    v.z = bf16pair(bflo(v.z) * dd, bfhi(v.z) * dd);
    v.w = bf16pair(bflo(v.w) * dd, bfhi(v.w) * dd);
    Hb[i] = v;
}

// ---------------- conv2 MFMA GEMM: bf16 input + fused BN1+ReLU, dis-prescaled out ----------------
__global__ __launch_bounds__(256)
void k_gemm_bf16(const u32* __restrict__ Xb, const u32* __restrict__ Wt,
                 u32* __restrict__ Yb, const float* __restrict__ ss,
                 const float* __restrict__ dis) {
    int t = threadIdx.x;
    int l = t & 63, wv = t >> 6;
    int rowbase = blockIdx.x * 64 + wv * 16;
    int ml = l & 15, kg = l >> 4;

    f32x4 acc[8];
#pragma unroll
    for (int nt = 0; nt < 8; ++nt) acc[nt] = (f32x4){0.f, 0.f, 0.f, 0.f};
    const u32* xr = Xb + (long)(rowbase + ml) * 64;
#pragma unroll
    for (int kk = 0; kk < 4; ++kk) {
        int k0 = kk * 32 + kg * 8;
        uint4 xw = *(const uint4*)&xr[k0 >> 1];
        float f0 = bflo(xw.x), f1 = bfhi(xw.x), f2 = bflo(xw.y), f3 = bfhi(xw.y);
        float f4 = bflo(xw.z), f5 = bfhi(xw.z), f6 = bflo(xw.w), f7 = bfhi(xw.w);
        float4 sca = *(const float4*)&ss[k0];
        float4 sha = *(const float4*)&ss[128 + k0];
        float4 scb = *(const float4*)&ss[k0 + 4];
        float4 shb = *(const float4*)&ss[128 + k0 + 4];
        f0 = fmaxf(fmaf(f0, sca.x, sha.x), 0.f);
        f1 = fmaxf(fmaf(f1, sca.y, sha.y), 0.f);
        f2 = fmaxf(fmaf(f2, sca.z, sha.z), 0.f);
        f3 = fmaxf(fmaf(f3, sca.w, sha.w), 0.f);
        f4 = fmaxf(fmaf(f4, scb.x, shb.x), 0.f);
        f5 = fmaxf(fmaf(f5, scb.y, shb.y), 0.f);
        f6 = fmaxf(fmaf(f6, scb.z, shb.z), 0.f);
        f7 = fmaxf(fmaf(f7, scb.w, shb.w), 0.f);
        union { u32 u[4]; bf16x8 v; } af;
        af.u[0] = bf16pair(f0, f1);
        af.u[1] = bf16pair(f2, f3);
        af.u[2] = bf16pair(f4, f5);
        af.u[3] = bf16pair(f6, f7);
#pragma unroll
        for (int nt = 0; nt < 8; ++nt) {
            bf16x8 b = *(const bf16x8*)&Wt[(nt * 16 + ml) * 64 + (k0 >> 1)];
            acc[nt] = __builtin_amdgcn_mfma_f32_16x16x32_bf16(af.v, b, acc[nt], 0, 0, 0);
        }
    }
#pragma unroll
    for (int r = 0; r < 4; ++r) {
        int m = rowbase + kg * 4 + r;
        float dd = dis[m];
        long obase = (long)m * 64;
#pragma unroll
        for (int nt = 0; nt < 8; ++nt) {
            float v = acc[nt][r] * dd;
            float v2 = __shfl_xor(v, 1);
            if ((l & 1) == 0)
                Yb[obase + nt * 8 + (ml >> 1)] = bf16pair(v, v2);
        }
    }
}

// ---------------- gather + fused BN partial stats ----------------
__global__ __launch_bounds__(256)
void k_gather_stats(const uint4* __restrict__ Hb, const int* __restrict__ rowstart,
                    const int* __restrict__ csr_src, const float* __restrict__ dis,
                    const float* __restrict__ bias, u32* __restrict__ F1b,
                    float* __restrict__ part) {
    __shared__ float ls[1024], lq[1024];
    int t = threadIdx.x;
    int lane = t & 63, wv = t >> 6;
    int gw = blockIdx.x * 4 + wv;
    int g = lane >> 4, p = lane & 15;
    int c0 = p * 8 + g * 2;
    float2 bb = *(const float2*)&bias[c0];
    float s0 = 0.f, s1 = 0.f, q0 = 0.f, q1 = 0.f;

    for (int node = gw; node < NN; node += GB * 4) {
        float a0 = 0.f, a1 = 0.f, a2 = 0.f, a3 = 0.f, a4 = 0.f, a5 = 0.f, a6 = 0.f, a7 = 0.f;
        if (g == 0) {
            uint4 h = Hb[node * 16 + p];
            a0 = bflo(h.x); a1 = bfhi(h.x);
            a2 = bflo(h.y); a3 = bfhi(h.y);
            a4 = bflo(h.z); a5 = bfhi(h.z);
            a6 = bflo(h.w); a7 = bfhi(h.w);
        }
        int e1 = rowstart[node + 1];
        int e = rowstart[node] + g;
        for (; e + 4 < e1; e += 8) {
            int sA = csr_src[e];
            int sB = csr_src[e + 4];
            uint4 h0 = Hb[sA * 16 + p];
            uint4 h1 = Hb[sB * 16 + p];
            a0 += bflo(h0.x); a1 += bfhi(h0.x);
            a2 += bflo(h0.y); a3 += bfhi(h0.y);
            a4 += bflo(h0.z); a5 += bfhi(h0.z);
            a6 += bflo(h0.w); a7 += bfhi(h0.w);
            a0 += bflo(h1.x); a1 += bfhi(h1.x);
            a2 += bflo(h1.y); a3 += bfhi(h1.y);
            a4 += bflo(h1.z); a5 += bfhi(h1.z);
            a6 += bflo(h1.w); a7 += bfhi(h1.w);
        }
        if (e < e1) {
            int sA = csr_src[e];
            uint4 h0 = Hb[sA * 16 + p];
            a0 += bflo(h0.x); a1 += bfhi(h0.x);
            a2 += bflo(h0.y); a3 += bfhi(h0.y);
            a4 += bflo(h0.z); a5 += bfhi(h0.z);
            a6 += bflo(h0.w); a7 += bfhi(h0.w);
        }
#pragma unroll
        for (int m = 16; m <= 32; m <<= 1) {
            a0 += __shfl_xor(a0, m); a1 += __shfl_xor(a1, m);
            a2 += __shfl_xor(a2, m); a3 += __shfl_xor(a3, m);
            a4 += __shfl_xor(a4, m); a5 += __shfl_xor(a5, m);
            a6 += __shfl_xor(a6, m); a7 += __shfl_xor(a7, m);
        }
        float dd = dis[node];
        float x = (g == 0) ? a0 : (g == 1) ? a2 : (g == 2) ? a4 : a6;
        float y = (g == 0) ? a1 : (g == 1) ? a3 : (g == 2) ? a5 : a7;
        x = fmaf(x, dd, bb.x);
        y = fmaf(y, dd, bb.y);
        u32 pw = bf16pair(x, y);
        F1b[node * 64 + (c0 >> 1)] = pw;
        float rx = bflo(pw), ry = bfhi(pw);
        s0 += rx; s1 += ry; q0 += rx * rx; q1 += ry * ry;
    }
    ls[wv * 128 + c0] = s0; ls[wv * 128 + c0 + 1] = s1;
    lq[wv * 128 + c0] = q0; lq[wv * 128 + c0 + 1] = q1;
    __syncthreads();
    if (t < 128) {
        float S = ls[t] + ls[128 + t] + ls[256 + t] + ls[384 + t];
        float Q = lq[t] + lq[128 + t] + lq[256 + t] + lq[384 + t];
        part[blockIdx.x * 256 + t] = S;
        part[blockIdx.x * 256 + 128 + t] = Q;
    }
}

// ---------------- BN finalize from gather partials ----------------
__global__ __launch_bounds__(256)
void k_bnfinalw(const float* __restrict__ part, const float* __restrict__ g,
                const float* __restrict__ b, float* __restrict__ ss) {
    __shared__ float rs[256], rq[256];
    int c = blockIdx.x, t = threadIdx.x;
    float s = 0.f, q = 0.f;
    for (int i = t; i < GB; i += 256) {
        s += part[i * 256 + c];
        q += part[i * 256 + 128 + c];
    }
    rs[t] = s; rq[t] = q;
    __syncthreads();
    for (int off = 128; off > 0; off >>= 1) {
        if (t < off) { rs[t] += rs[t + off]; rq[t] += rq[t + off]; }
        __syncthreads();
    }
    if (t == 0) {
        float mean = rs[0] * (1.0f / NN);
        float var  = rq[0] * (1.0f / NN) - mean * mean;
        float sc = g[c] * rsqrtf(var + BNEPS);
        ss[c] = sc;
        ss[128 + c] = b[c] - mean * sc;
    }
}

// ---------------- k_scoremb: BN2+ReLU (regs) + emb write + MFMA attention scores ----------------
__global__ __launch_bounds__(256)
void k_scoremb(const u32* __restrict__ F1b, const float* __restrict__ ss,
               float* __restrict__ emb,
               const u32* __restrict__ Wta, const float* __restrict__ b1,
               const float* __restrict__ w2, const float* __restrict__ b2,
               float* __restrict__ scores) {
    int t = threadIdx.x;
    int l = t & 63, wv = t >> 6;
    int rowbase = blockIdx.x * 64 + wv * 16;
    int ml = l & 15, kg = l >> 4;

    f32x4 acc[4];
#pragma unroll
    for (int nt = 0; nt < 4; ++nt) acc[nt] = (f32x4){0.f, 0.f, 0.f, 0.f};
    const u32* xr = F1b + (long)(rowbase + ml) * 64;
    float* er = emb + (long)(rowbase + ml) * 128;
#pragma unroll
    for (int kk = 0; kk < 4; ++kk) {
        int k0 = kk * 32 + kg * 8;
        uint4 xw = *(const uint4*)&xr[k0 >> 1];
        float f0 = bflo(xw.x), f1 = bfhi(xw.x), f2 = bflo(xw.y), f3 = bfhi(xw.y);
        float f4 = bflo(xw.z), f5 = bfhi(xw.z), f6 = bflo(xw.w), f7 = bfhi(xw.w);
        float4 sca = *(const float4*)&ss[k0];
        float4 sha = *(const float4*)&ss[128 + k0];
        float4 scb = *(const float4*)&ss[k0 + 4];
        float4 shb = *(const float4*)&ss[128 + k0 + 4];
        f0 = fmaxf(fmaf(f0, sca.x, sha.x), 0.f);
        f1 = fmaxf(fmaf(f1, sca.y, sha.y), 0.f);
        f2 = fmaxf(fmaf(f2, sca.z, sha.z), 0.f);
        f3 = fmaxf(fmaf(f3, sca.w, sha.w), 0.f);
        f4 = fmaxf(fmaf(f4, scb.x, shb.x), 0.f);
        f5 = fmaxf(fmaf(f5, scb.y, shb.y), 0.f);
        f6 = fmaxf(fmaf(f6, scb.z, shb.z), 0.f);
        f7 = fmaxf(fmaf(f7, scb.w, shb.w), 0.f);
        float4 e0 = { f0, f1, f2, f3 };
        float4 e1 = { f4, f5, f6, f7 };
        *(float4*)&er[k0] = e0;
        *(float4*)&er[k0 + 4] = e1;
        union { u32 u[4]; bf16x8 v; } af;
        af.u[0] = bf16pair(f0, f1);
        af.u[1] = bf16pair(f2, f3);
        af.u[2] = bf16pair(f4, f5);
        af.u[3] = bf16pair(f6, f7);
#pragma unroll
        for (int nt = 0; nt < 4; ++nt) {
            bf16x8 b = *(const bf16x8*)&Wta[(nt * 16 + ml) * 64 + (k0 >> 1)];
            acc[nt] = __builtin_amdgcn_mfma_f32_16x16x32_bf16(af.v, b, acc[nt], 0, 0, 0);
        }
    }
    float b1v[4], w2v[4];
#pragma unroll
    for (int nt = 0; nt < 4; ++nt) {
        b1v[nt] = b1[nt * 16 + ml];
        w2v[nt] = w2[nt * 16 + ml];
    }
    float b2v = b2[0];
#pragma unroll
    for (int r = 0; r < 4; ++r) {
        float s = tanhf(acc[0][r] + b1v[0]) * w2v[0]
                + tanhf(acc[1][r] + b1v[1]) * w2v[1]
                + tanhf(acc[2][r] + b1v[2]) * w2v[2]
                + tanhf(acc[3][r] + b1v[3]) * w2v[3];
        s += __shfl_xor(s, 1);
        s += __shfl_xor(s, 2);
        s += __shfl_xor(s, 4);
        s += __shfl_xor(s, 8);
        if (ml == 0) scores[rowbase + kg * 4 + r] = s + b2v;
    }
}

// ---------------- k_pool4: softmax (redundant per quarter) + partial pool ----------------
__global__ __launch_bounds__(256)
void k_pool4(const u32* __restrict__ F1b, const float* __restrict__ ss,
             const float* __restrict__ scores, float* __restrict__ pp) {
    __shared__ float sl[SUBG];
    __shared__ float red[256];
    __shared__ float rbuf[512];
    int b = blockIdx.x;
    int c = b >> 2, q = b & 3;
    int t = threadIdx.x;
    int base = c * SUBG;

    float lmax = -1e30f;
    for (int i = t; i < SUBG; i += 256) {
        float v = scores[base + i];
        sl[i] = v;
        lmax = fmaxf(lmax, v);
    }
    red[t] = lmax;
    __syncthreads();
    for (int off = 128; off > 0; off >>= 1) {
        if (t < off) red[t] = fmaxf(red[t], red[t + off]);
        __syncthreads();
    }
    float mx = red[0];
    __syncthreads();
    float lsum = 0.f;
    for (int i = t; i < SUBG; i += 256) {
        float e = __expf(sl[i] - mx);
        sl[i] = e;
        lsum += e;
    }
    red[t] = lsum;
    __syncthreads();
    for (int off = 128; off > 0; off >>= 1) {
        if (t < off) red[t] += red[t + off];
        __syncthreads();
    }
    float inv = 1.0f / red[0];
    __syncthreads();

    int cc = t & 63, gp = t >> 6;
    float2 scv = *(const float2*)&ss[2 * cc];
    float2 shv = *(const float2*)&ss[128 + 2 * cc];
    int g0 = q * 100 + gp * 25;
    float a0 = 0.f, a1 = 0.f;
#pragma unroll 5
    for (int j = 0; j < 25; ++j) {
        int gg = g0 + j;
        u32 v = F1b[(long)(base + gg) * 64 + cc];
        float w = sl[gg] * inv;
        float x0 = fmaxf(fmaf(bflo(v), scv.x, shv.x), 0.f);
        float x1 = fmaxf(fmaf(bfhi(v), scv.y, shv.y), 0.f);
        a0 += w * x0;
        a1 += w * x1;
    }
    rbuf[gp * 128 + 2 * cc] = a0;
    rbuf[gp * 128 + 2 * cc + 1] = a1;
    __syncthreads();
    if (t < 128)
        pp[b * 128 + t] = rbuf[t] + rbuf[128 + t] + rbuf[256 + t] + rbuf[384 + t];
}

// ---------------- k_head1r: sum quarters + fc head1 + atomic BN stats ----------------
__global__ __launch_bounds__(128)
void k_head1r(const float* __restrict__ pp, const float* __restrict__ fc_w,
              const float* __restrict__ fc_b, float* __restrict__ y1pre,
              float* __restrict__ hstats) {
    __shared__ float pr[128];
    int c = blockIdx.x, t = threadIdx.x;
    pr[t] = pp[(c * 4 + 0) * 128 + t] + pp[(c * 4 + 1) * 128 + t]
          + pp[(c * 4 + 2) * 128 + t] + pp[(c * 4 + 3) * 128 + t];
    __syncthreads();
    float a1 = fc_b[t];
#pragma unroll 4
    for (int k = 0; k < 128; ++k) a1 = fmaf(pr[k], fc_w[k * 128 + t], a1);
    y1pre[c * 128 + t] = a1;
    atomicAdd(&hstats[t], a1);
    atomicAdd(&hstats[128 + t], a1 * a1);
}

// ---------------- head2: finalize BN-e, apply, bottleneck, atomic stats2 ----------------
__global__ __launch_bounds__(128)
void k_head2s(const float* __restrict__ y1pre, const float* __restrict__ hstats,
              const float* __restrict__ bne_g, const float* __restrict__ bne_b,
              const float* __restrict__ bot_w, const float* __restrict__ bot_b,
              float* __restrict__ y2pre, float* __restrict__ hstats2) {
    __shared__ float row[128];
    int c = blockIdx.x, t = threadIdx.x;
    float s = hstats[t], q = hstats[128 + t];
    float mean = s * 0.01f, var = q * 0.01f - mean * mean;
    float scv = bne_g[t] * rsqrtf(var + BNEPS);
    float shv = bne_b[t] - mean * scv;
    row[t] = fmaxf(fmaf(y1pre[c * 128 + t], scv, shv), 0.f);
    __syncthreads();
    if (t < 32) {
        float a2 = bot_b[t];
#pragma unroll 4
        for (int k = 0; k < 128; ++k) a2 = fmaf(row[k], bot_w[k * 32 + t], a2);
        y2pre[c * 32 + t] = a2;
        atomicAdd(&hstats2[t], a2);
        atomicAdd(&hstats2[32 + t], a2 * a2);
    }
}

// ---------------- final: BN-b finalize + apply ----------------
__global__ __launch_bounds__(256)
void k_out(const float* __restrict__ y2pre, const float* __restrict__ hstats2,
           const float* __restrict__ bnb_g, const float* __restrict__ bnb_b,
           float* __restrict__ y_out) {
    __shared__ float scv[32], shv[32];
    int t = threadIdx.x;
    if (t < 32) {
        float s = hstats2[t], q = hstats2[32 + t];
        float mean = s * 0.01f, var = q * 0.01f - mean * mean;
        float v = bnb_g[t] * rsqrtf(var + BNEPS);
        scv[t] = v; shv[t] = bnb_b[t] - mean * v;
    }
    __syncthreads();
    for (int i = t; i < CELLS * 32; i += 256)
        y_out[i] = fmaxf(fmaf(y2pre[i], scv[i & 31], shv[i & 31]), 0.f);
}

// ---------------- launcher ----------------
extern "C" void kernel_launch(void* const* d_in, const int* in_sizes, int n_in,
                              void* d_out, int out_size, void* d_ws, size_t ws_size,
                              hipStream_t stream) {
    const float* x        = (const float*)d_in[0];
    const int*   ei       = (const int*)d_in[1];
    const float* conv1_w  = (const float*)d_in[2];
    const float* conv1_b  = (const float*)d_in[3];
    const float* bn1_g    = (const float*)d_in[4];
    const float* bn1_b    = (const float*)d_in[5];
    const float* conv2_w  = (const float*)d_in[6];
    const float* conv2_b  = (const float*)d_in[7];
    const float* bn2_g    = (const float*)d_in[8];
    const float* bn2_b    = (const float*)d_in[9];
    const float* att_w1   = (const float*)d_in[10];
    const float* att_b1   = (const float*)d_in[11];
    const float* att_w2   = (const float*)d_in[12];
    const float* att_b2   = (const float*)d_in[13];
    const float* fc_w     = (const float*)d_in[14];
    const float* fc_b     = (const float*)d_in[15];
    const float* bne_g    = (const float*)d_in[16];
    const float* bne_b    = (const float*)d_in[17];
    const float* bot_w    = (const float*)d_in[18];
    const float* bot_b    = (const float*)d_in[19];
    const float* bnb_g    = (const float*)d_in[20];
    const float* bnb_b    = (const float*)d_in[21];

    const int* src = ei;
    const int* dst = ei + EE;

    float* y_out   = (float*)d_out;            // [100,32]
    float* emb_out = y_out + CELLS * 32;       // [40000,128]

    float* ws = (float*)d_ws;
    u32*   Hb     = (u32*)ws;                  // N*64
    u32*   F1b    = Hb + (long)NN * 64;        // N*64
    float* dis    = (float*)(F1b + (long)NN * 64);  // N
    float* part   = dis + NN;                  // GB*256
    float* ss     = part + GB * 256;           // 256
    float* hstats = ss + 256;                  // 320
    float* y1pre  = hstats + 320;              // C*128
    float* y2pre  = y1pre + CELLS * 128;       // C*32
    float* scores = y2pre + CELLS * 32;        // N
    float* pp     = scores + NN;               // 400*128
    u32*   Wt1    = (u32*)(pp + 400 * 128);    // 8192
    u32*   Wt2    = Wt1 + 8192;                // 8192
    u32*   Wta    = Wt2 + 8192;                // 4096
    int*   deg    = (int*)(Wta + 4096);        // N (deg + cursor contiguous)
    int*   cursor = deg + NN;                  // N
    int*   rowstart = cursor + NN;             // N+1
    int*   csr_src  = rowstart + NN + 1;       // E

    // 1. init
    k_init<<<394, 256, 0, stream>>>(deg, conv1_w, Wt1, conv2_w, Wt2, att_w1, Wta, hstats);
    // 2. conv1 GEMM (unscaled) || degree count
    k_gemmdeg<<<GEMMB + DEGB, 256, 0, stream>>>(x, Wt1, Hb, dst, deg);
    // 3. scan -> rowstart, dis
    k_scan<<<1, 1024, 0, stream>>>(deg, rowstart, dis);
    // 4. fill CSR || scale Hb by dis
    k_fillscale<<<FILLB + SCALEB, 256, 0, stream>>>(src, dst, rowstart, cursor,
                                                    csr_src, (uint4*)Hb, dis);
    // 5-6. conv1 gather+stats, BN1 finalize
    k_gather_stats<<<GB, 256, 0, stream>>>((const uint4*)Hb, rowstart, csr_src, dis,
                                           conv1_b, F1b, part);
    k_bnfinalw<<<128, 256, 0, stream>>>(part, bn1_g, bn1_b, ss);
    // 7. conv2 GEMM (bf16 in, BN1+ReLU fused, dis-prescaled out)
    k_gemm_bf16<<<GEMMB, 256, 0, stream>>>(F1b, Wt2, Hb, ss, dis);
    // 8-9. conv2 gather+stats, BN2 finalize
    k_gather_stats<<<GB, 256, 0, stream>>>((const uint4*)Hb, rowstart, csr_src, dis,
                                           conv2_b, F1b, part);
    k_bnfinalw<<<128, 256, 0, stream>>>(part, bn2_g, bn2_b, ss);
    // 10. BN2+ReLU + emb + MFMA scores
    k_scoremb<<<GEMMB, 256, 0, stream>>>(F1b, ss, emb_out, Wta, att_b1, att_w2,
                                         att_b2, scores);
    // 11. softmax + partial pool (4 blocks/cell)
    k_pool4<<<4 * CELLS, 256, 0, stream>>>(F1b, ss, scores, pp);
    // 12. sum partials + head1
    k_head1r<<<CELLS, 128, 0, stream>>>(pp, fc_w, fc_b, y1pre, hstats);
    // 13. head2 + stats2
    k_head2s<<<CELLS, 128, 0, stream>>>(y1pre, hstats, bne_g, bne_b, bot_w, bot_b,
                                        y2pre, hstats + 256);
    // 14. final BN + output
    k_out<<<1, 256, 0, stream>>>(y2pre, hstats + 256, bnb_g, bnb_b, y_out);
}